// Round 6
// baseline (310.780 us; speedup 1.0000x reference)
//
#include <hip/hip_runtime.h>
#include <hip/hip_fp16.h>

// Problem constants (fixed by the reference setup_inputs()).
constexpr int B  = 2;
constexpr int A  = 512;
constexpr int P  = 8;
constexpr int CM = 6;     // cameras
constexpr int SC = 4;     // scales
constexpr int C  = 256;   // channels
constexpr int G  = 8;     // groups (D = 32 channels each)
constexpr int NCOMBO = P * CM * SC;      // 192
constexpr int NFEAT  = 89760;            // flattened feature rows per batch
constexpr int COMBOS_PER_WAVE = NCOMBO / 4;  // 48
constexpr int NGRP = COMBOS_PER_WAVE / 2;    // 24 groups of 2 combos

// ---------------- kernel 1: feat f32 -> fp16 into ws ----------------
__global__ __launch_bounds__(256)
void convert_fp16_kernel(const float* __restrict__ in,
                         uint2* __restrict__ out,   // 4 halves per uint2
                         int n4) {                  // count of float4 groups
  const float4* in4 = (const float4*)in;
  int i = blockIdx.x * 256 + threadIdx.x;
  const int stride = gridDim.x * 256;
  for (; i < n4; i += stride) {
    const float4 v = in4[i];
    union { __half2 h; unsigned u; } a, b;
    a.h = __floats2half2_rn(v.x, v.y);
    b.h = __floats2half2_rn(v.z, v.w);
    uint2 q; q.x = a.u; q.y = b.u;
    out[i] = q;
  }
}

// ---------------- kernel 2: pair-gather + weighted accumulate ----------------
// fp16 row = 512B. An x-corner pair (rows r, r+1) is 1KB contiguous -> ONE
// dwordx4 wave instruction: lanes 0-31 read row r, lanes 32-63 read row r+1.
// Each lane covers channels 8*(lane&31) .. +7 of its corner-column.
__global__ __launch_bounds__(256, 4)
void deform_agg_kernel(const uint4* __restrict__ feat16,     // [B,NFEAT,32] uint4
                       const int*   __restrict__ spatial,     // [CM, SC, 2] (H, W)
                       const int*   __restrict__ scale_start, // [CM, SC]
                       const float* __restrict__ samp_loc,    // [B, A, P, CM, 2]
                       const float* __restrict__ weights,     // [B, A, P, CM, S, G]
                       float*       __restrict__ out) {       // [B, A, C]
  __shared__ int    s_idx[NCOMBO][2];   // uint4 index of y0-pair / y1-pair base
  __shared__ float  s_cw[NCOMBO][4];    // (xlo,xhi)*wy0, (xlo,xhi)*wy1
  __shared__ float  s_wg[NCOMBO * G];   // group weights, combo-major
  __shared__ float  s_red[4][32][8];    // per-wave partials (half-folded)

  const int tid = threadIdx.x;
  const int ba  = blockIdx.x;       // b*A + a
  const int b   = ba >> 9;          // / 512

  // ---------------- stage 1: per-combo geometry ----------------
  if (tid < NCOMBO) {
    const int p   = tid / (CM * SC);
    const int cam = (tid / SC) % CM;
    const int s   = tid & (SC - 1);
    const float* lp = samp_loc + ((size_t)(ba * P + p) * CM + cam) * 2;
    const float lx = lp[0];
    const float ly = lp[1];
    const int H  = spatial[(cam * SC + s) * 2 + 0];
    const int W  = spatial[(cam * SC + s) * 2 + 1];
    const int st = scale_start[cam * SC + s];

    const float x = lx * (float)W - 0.5f;
    const float y = ly * (float)H - 0.5f;
    const float x0f = floorf(x), y0f = floorf(y);
    const int   ix0 = (int)x0f,  iy0 = (int)y0f;
    const float wx1 = x - x0f,   wy1 = y - y0f;

    // x-pair: base column bx; lo half-wave covers column bx, hi covers bx+1.
    int   bx;
    float wxlo, wxhi;
    if (ix0 >= 0 && ix0 < W) {
      bx = ix0;  wxlo = 1.f - wx1;  wxhi = (ix0 + 1 < W) ? wx1 : 0.f;
    } else if (ix0 == -1) {
      bx = 0;    wxlo = wx1;        wxhi = 0.f;   // only x1(=0) valid; lo reads it
    } else {
      bx = (ix0 < 0) ? 0 : (W - 1);  wxlo = 0.f;  wxhi = 0.f;
    }
    // y rows: clip for addressing, zero weight when OOB.
    const int   iy1 = iy0 + 1;
    const float wy0 = (iy0 >= 0 && iy0 < H) ? (1.f - wy1) : 0.f;
    const float wyb = (iy1 >= 0 && iy1 < H) ? wy1 : 0.f;
    const int   ry0 = min(max(iy0, 0), H - 1);
    const int   ry1 = min(max(iy1, 0), H - 1);

    s_idx[tid][0] = (st + ry0 * W + bx) * 32;   // uint4 units (32 per row)
    s_idx[tid][1] = (st + ry1 * W + bx) * 32;
    s_cw[tid][0]  = wxlo * wy0;
    s_cw[tid][1]  = wxhi * wy0;
    s_cw[tid][2]  = wxlo * wyb;
    s_cw[tid][3]  = wxhi * wyb;
  }
  // weights for this (b,a): 1536 contiguous floats, layout == combo*G + g
  {
    const float* wbase = weights + (size_t)ba * NCOMBO * G;
    for (int i = tid; i < NCOMBO * G; i += 256) s_wg[i] = wbase[i];
  }
  __syncthreads();

  // ---------------- stage 2: pipelined pair-gather ----------------
  const int wid  = tid >> 6;
  const int lane = tid & 63;
  const int hi   = lane >> 5;          // 0: column bx, 1: column bx+1
  const int g    = (lane & 31) >> 2;   // channel block 8*(lane&31) -> group
  const uint4* fb = feat16 + (size_t)b * NFEAT * 32;

  float acc[8] = {0.f, 0.f, 0.f, 0.f, 0.f, 0.f, 0.f, 0.f};
  const int c0 = wid * COMBOS_PER_WAVE;

  // group = 2 combos = 4 pair-loads
  auto load_grp = [&](int grp, uint4* f, float* cw) {
#pragma unroll
    for (int jc = 0; jc < 2; ++jc) {
      const int c = c0 + grp * 2 + jc;
      const float w = s_wg[c * G + g];
      cw[jc * 2 + 0] = s_cw[c][hi] * w;        // y0-pair, this half's column
      cw[jc * 2 + 1] = s_cw[c][2 + hi] * w;    // y1-pair
      f[jc * 2 + 0]  = fb[s_idx[c][0] + lane];
      f[jc * 2 + 1]  = fb[s_idx[c][1] + lane];
    }
  };
  auto consume = [&](const uint4* f, const float* cw) {
#pragma unroll
    for (int j = 0; j < 4; ++j) {
      const float w = cw[j];
      const unsigned* q = &f[j].x;
#pragma unroll
      for (int k = 0; k < 4; ++k) {
        const __half2 h = *reinterpret_cast<const __half2*>(&q[k]);
        const float2 v = __half22float2(h);
        acc[2 * k + 0] = fmaf(v.x, w, acc[2 * k + 0]);
        acc[2 * k + 1] = fmaf(v.y, w, acc[2 * k + 1]);
      }
    }
  };

  uint4 fA[4], fB[4];
  float cwA[4], cwB[4];
  load_grp(0, fA, cwA);
#pragma unroll
  for (int it = 0; it < NGRP - 1; ++it) {
    if ((it & 1) == 0) {
      load_grp(it + 1, fB, cwB);   // issue next group's loads first...
      consume(fA, cwA);            // ...then consume current group
    } else {
      load_grp(it + 1, fA, cwA);
      consume(fB, cwB);
    }
  }
  consume(fB, cwB);                // group 23 (odd count) lands in B

  // fold the two x-corner halves: lane L += lane L^32
#pragma unroll
  for (int j = 0; j < 8; ++j) acc[j] += __shfl_xor(acc[j], 32);
  if (lane < 32) {
#pragma unroll
    for (int j = 0; j < 8; ++j) s_red[wid][lane][j] = acc[j];
  }
  __syncthreads();

  // thread t -> output channel t: ch = 8*(t>>3) + (t&7)
  {
    const int l8 = tid >> 3, j = tid & 7;
    const float v = s_red[0][l8][j] + s_red[1][l8][j] +
                    s_red[2][l8][j] + s_red[3][l8][j];
    out[(size_t)ba * C + 8 * l8 + j] = v;
  }
}

extern "C" void kernel_launch(void* const* d_in, const int* in_sizes, int n_in,
                              void* d_out, int out_size, void* d_ws, size_t ws_size,
                              hipStream_t stream) {
  const float* feat        = (const float*)d_in[0];
  const int*   spatial     = (const int*)d_in[1];
  const int*   scale_start = (const int*)d_in[2];
  const float* samp_loc    = (const float*)d_in[3];
  const float* weights     = (const float*)d_in[4];
  float*       out         = (float*)d_out;
  uint2*       feat16      = (uint2*)d_ws;   // [B*NFEAT*C] halves

  const int n4 = in_sizes[0] / 4;            // float4 groups in feat
  convert_fp16_kernel<<<2048, 256, 0, stream>>>(feat, feat16, n4);
  deform_agg_kernel<<<B * A, 256, 0, stream>>>((const uint4*)d_ws, spatial,
                                               scale_start, samp_loc, weights,
                                               out);
}